// Round 3
// baseline (572.472 us; speedup 1.0000x reference)
//
#include <hip/hip_runtime.h>
#include <math.h>

#define BB 32
#define LL 2048
#define DD 1024
#define HH 16
#define DHH 64
#define NCK 32         // chunks per batch
#define CH  64         // rows per chunk

// ---- ws layout (float offsets) ----
#define WS_Q0    0          // 1024
#define WS_Q     1024       // 1024
#define WS_R     2048       // 16*1024
#define WS_C     18432      // 64 (16 used)
#define WS_SINV  18496      // 512
#define WS_CTX   19008      // 32768
#define WS_Y     51776      // 32768
#define WS_SSUM  84544      // 32*32*16 = 16384
#define WS_PART  100928     // 32*32*16*1024 = 16777216
// total ~= 16.9M floats ~= 67.5 MB (ws is ~1 GB)

__device__ __forceinline__ float wave_sum(float v) {
#pragma unroll
    for (int s = 32; s >= 1; s >>= 1) v += __shfl_xor(v, s, 64);
    return v;
}

// ---------------- K0: q0 = LN(symbol_queries[pos]) ----------------
__global__ void k_q0(const float* __restrict__ sq, const float* __restrict__ qn_w,
                     const float* __restrict__ qn_b, const int* __restrict__ pos,
                     float* __restrict__ ws) {
    const int t = threadIdx.x;              // 256 threads
    const float4 x = ((const float4*)(sq + (size_t)pos[0] * DD))[t];
    float s  = x.x + x.y + x.z + x.w;
    float s2 = x.x * x.x + x.y * x.y + x.z * x.z + x.w * x.w;
    __shared__ float rs[4], rs2[4];
    s = wave_sum(s); s2 = wave_sum(s2);
    const int w = t >> 6, lane = t & 63;
    if (lane == 0) { rs[w] = s; rs2[w] = s2; }
    __syncthreads();
    s  = rs[0] + rs[1] + rs[2] + rs[3];
    s2 = rs2[0] + rs2[1] + rs2[2] + rs2[3];
    const float mu  = s * (1.0f / DD);
    const float var = s2 * (1.0f / DD) - mu * mu;
    const float rstd = rsqrtf(var + 1e-5f);
    const float4 w4 = ((const float4*)qn_w)[t];
    const float4 b4 = ((const float4*)qn_b)[t];
    float4 o;
    o.x = (x.x - mu) * rstd * w4.x + b4.x;
    o.y = (x.y - mu) * rstd * w4.y + b4.y;
    o.z = (x.z - mu) * rstd * w4.z + b4.z;
    o.w = (x.w - mu) * rstd * w4.w + b4.w;
    ((float4*)(ws + WS_Q0))[t] = o;
}

// ---------------- K1: q = Wq @ q0 + bq  (wave per output) ----------------
__global__ void k_q(const float* __restrict__ ipw, const float* __restrict__ ipb,
                    float* __restrict__ ws) {
    const int w = threadIdx.x >> 6, lane = threadIdx.x & 63;
    const int d = blockIdx.x * 4 + w;       // 256 blocks * 4 waves = 1024 outputs
    const float* row = ipw + (size_t)d * DD;
    const float* q0 = ws + WS_Q0;
    float acc = 0.f;
#pragma unroll
    for (int it = 0; it < 4; ++it) {
        float4 a = ((const float4*)row)[lane + 64 * it];
        float4 b = ((const float4*)q0)[lane + 64 * it];
        acc += a.x * b.x + a.y * b.y + a.z * b.z + a.w * b.w;
    }
    acc = wave_sum(acc);
    if (lane == 0) (ws + WS_Q)[d] = acc + ipb[d];
}

// ---------------- K2: r_s[h,e] = scale * sum_j q[h,j] Wk[h*64+j, e] --------
// grid 64 = (h, quarter); 256 threads each own one e.
__global__ void k_r(const float* __restrict__ ipw, const float* __restrict__ ipb,
                    float* __restrict__ ws) {
    const int h = blockIdx.x >> 2, qa = blockIdx.x & 3;
    const int t = threadIdx.x;
    const int e = qa * 256 + t;
    const float* q = ws + WS_Q;
    const float* wk = ipw + (size_t)(DD + h * DHH) * DD;
    float acc = 0.f;
#pragma unroll 8
    for (int j = 0; j < DHH; ++j)
        acc += q[h * DHH + j] * wk[(size_t)j * DD + e];
    (ws + WS_R)[h * DD + e] = acc * 0.125f;
    if (qa == 0 && t < 64) {
        float p = q[h * DHH + t] * ipb[DD + h * DHH + t];
        p = wave_sum(p);
        if (t == 0) (ws + WS_C)[h] = p * 0.125f;
    }
}

// ---------------- fused: scores + exp + weighted pooling, one grid pass ----
// block = (b, chunk of 64 rows); 256 threads; thread owns float4 e-slice.
// Writes: attn area <- exp(score) (unnormalized); partials P_c; weight sums s_c.
__global__ __launch_bounds__(256, 4)
void k_fused(const float* __restrict__ gr, const float* __restrict__ ws,
             float* __restrict__ attn_e, float* __restrict__ part,
             float* __restrict__ ssum) {
    const int b  = blockIdx.x >> 5;
    const int ck = blockIdx.x & 31;
    const int l0 = ck * CH;
    const int t = threadIdx.x, w = t >> 6, lane = t & 63;
    float4 rr[16];
#pragma unroll
    for (int h = 0; h < 16; ++h) rr[h] = ((const float4*)(ws + WS_R + h * DD))[t];
    const float myc = (ws + WS_C)[lane >> 2];
    float4 acc[16];
#pragma unroll
    for (int h = 0; h < 16; ++h) acc[h] = make_float4(0.f, 0.f, 0.f, 0.f);
    float s_loc = 0.f;                      // (w0 lanes) sum of weights for (h,j)
    float* outp = attn_e + (size_t)b * (HH * LL) + (size_t)(lane >> 2) * LL + l0 + (lane & 3);
    const float* gb = gr + ((size_t)b * LL + l0) * DD;
    __shared__ float red[4][64];
    __shared__ float wbuf[64];

    float4 gv[4];
#pragma unroll
    for (int j = 0; j < 4; ++j)
        gv[j] = ((const float4*)(gb + (size_t)j * DD))[t];

    for (int g = 0; g < CH / 4; ++g) {
        // ---- scores for 4 rows x 16 heads ----
        float val[64];                      // v = h*4 + j
#pragma unroll
        for (int h = 0; h < 16; ++h)
#pragma unroll
            for (int j = 0; j < 4; ++j)
                val[h * 4 + j] = rr[h].x * gv[j].x + rr[h].y * gv[j].y +
                                 rr[h].z * gv[j].z + rr[h].w * gv[j].w;
        // multi-value butterfly: lane i ends holding total of value i
#pragma unroll
        for (int step = 0; step < 6; ++step) {
            const int s = 32 >> step;
            const bool up = (lane & s) != 0;
#pragma unroll
            for (int k = 0; k < (32 >> step); ++k) {
                float send = up ? val[k] : val[k + s];
                float recv = __shfl_xor(send, s, 64);
                float mine = up ? val[k + s] : val[k];
                val[k] = mine + recv;
            }
        }
        red[w][lane] = val[0];
        __syncthreads();
        if (w == 0) {
            float tot = red[0][lane] + red[1][lane] + red[2][lane] + red[3][lane] + myc;
            float wv = __expf(tot);         // no max-shift: |score| ~ O(1)
            outp[g * 4] = wv;
            s_loc += wv;
            wbuf[lane] = wv;
        }
        __syncthreads();
        // ---- prefetch next group's rows ----
        float4 gn[4];
        if (g < CH / 4 - 1) {
#pragma unroll
            for (int j = 0; j < 4; ++j)
                gn[j] = ((const float4*)(gb + (size_t)((g + 1) * 4 + j) * DD))[t];
        }
        // ---- weighted accumulation (weights broadcast from LDS) ----
#pragma unroll
        for (int h = 0; h < 16; ++h) {
            const float4 w4 = ((const float4*)wbuf)[h];
            acc[h].x += w4.x * gv[0].x + w4.y * gv[1].x + w4.z * gv[2].x + w4.w * gv[3].x;
            acc[h].y += w4.x * gv[0].y + w4.y * gv[1].y + w4.z * gv[2].y + w4.w * gv[3].y;
            acc[h].z += w4.x * gv[0].z + w4.y * gv[1].z + w4.z * gv[2].z + w4.w * gv[3].z;
            acc[h].w += w4.x * gv[0].w + w4.y * gv[1].w + w4.z * gv[2].w + w4.w * gv[3].w;
        }
#pragma unroll
        for (int j = 0; j < 4; ++j) gv[j] = gn[j];
    }
    // ---- write weight sums (w0) and partials ----
    if (w == 0) {
        float v = s_loc;
        v += __shfl_xor(v, 1, 64);
        v += __shfl_xor(v, 2, 64);
        if ((lane & 3) == 0) ssum[((size_t)b * NCK + ck) * HH + (lane >> 2)] = v;
    }
    float* pp = part + ((size_t)b * NCK + ck) * (HH * DD);
#pragma unroll
    for (int h = 0; h < 16; ++h) ((float4*)(pp + h * DD))[t] = acc[h];
}

// ---------------- combine + Wv: ctx[b, h*64+j] ----------------
__global__ void k_ctx(const float* __restrict__ ipw, const float* __restrict__ ipb,
                      const float* __restrict__ part, const float* __restrict__ ssum,
                      float* __restrict__ sinv_out, float* __restrict__ ctx) {
    const int bh = blockIdx.x, b = bh >> 4, h = bh & 15;   // 512 blocks
    const int t = threadIdx.x, w = t >> 6, lane = t & 63;  // 256
    float S = 0.f;
#pragma unroll
    for (int c = 0; c < NCK; ++c) S += ssum[((size_t)b * NCK + c) * HH + h];
    const float inv = 1.0f / S;
    if (t == 0) sinv_out[bh] = inv;
    __shared__ float Xl[DD];
    float4 x = {0.f, 0.f, 0.f, 0.f};
#pragma unroll
    for (int c = 0; c < NCK; ++c) {
        float4 p = ((const float4*)(part + ((size_t)b * NCK + c) * (HH * DD) + h * DD))[t];
        x.x += p.x; x.y += p.y; x.z += p.z; x.w += p.w;
    }
    float4 xs = {x.x * inv, x.y * inv, x.z * inv, x.w * inv};
    ((float4*)Xl)[t] = xs;
    __syncthreads();
    for (int jj = 0; jj < 16; ++jj) {
        const int j = w * 16 + jj;
        const float* row = ipw + (size_t)(2 * DD + h * DHH + j) * DD;
        float acc = 0.f;
#pragma unroll
        for (int it = 0; it < 4; ++it) {
            float4 a = ((const float4*)row)[lane + 64 * it];
            float4 p = ((const float4*)Xl)[lane + 64 * it];
            acc += a.x * p.x + a.y * p.y + a.z * p.z + a.w * p.w;
        }
        acc = wave_sum(acc);
        if (lane == 0) ctx[(size_t)b * DD + h * DHH + j] = acc + ipb[2 * DD + h * DHH + j];
    }
}

// ---------------- normalize attn in place: *= 1/S ----------------
__global__ void k_attn_norm(float* __restrict__ attn_e, const float* __restrict__ sinv) {
    const int bh = blockIdx.x;              // 512
    const int t = threadIdx.x;              // 256
    const float inv = sinv[bh];
    float4* p = (float4*)(attn_e + (size_t)bh * LL);
#pragma unroll
    for (int i = 0; i < 2; ++i) {
        float4 v = p[t + 256 * i];
        v.x *= inv; v.y *= inv; v.z *= inv; v.w *= inv;
        p[t + 256 * i] = v;
    }
}

// ---------------- y[b, d'] = out_w[d',:]·ctx[b,:] + out_b ----------------
__global__ void k_y(const float* __restrict__ ow, const float* __restrict__ ob,
                    const float* __restrict__ ctx, float* __restrict__ y) {
    const int blk = blockIdx.x, b = blk >> 4, ch = blk & 15;  // 512 blocks
    const int t = threadIdx.x, w = t >> 6, lane = t & 63;     // 256
    __shared__ float Xl[DD];
    ((float4*)Xl)[t] = ((const float4*)(ctx + (size_t)b * DD))[t];
    __syncthreads();
    for (int jj = 0; jj < 16; ++jj) {
        const int d = ch * 64 + w * 16 + jj;
        const float* row = ow + (size_t)d * DD;
        float acc = 0.f;
#pragma unroll
        for (int it = 0; it < 4; ++it) {
            float4 a = ((const float4*)row)[lane + 64 * it];
            float4 p = ((const float4*)Xl)[lane + 64 * it];
            acc += a.x * p.x + a.y * p.y + a.z * p.z + a.w * p.w;
        }
        acc = wave_sum(acc);
        if (lane == 0) y[(size_t)b * DD + d] = acc + ob[d];
    }
}

// ---------------- final LN -> pooled output ----------------
__global__ void k_lnout(const float* __restrict__ y, const float* __restrict__ on_w,
                        const float* __restrict__ on_b, float* __restrict__ outp) {
    const int b = blockIdx.x, t = threadIdx.x;   // 32 blocks, 256 threads
    const float4 x = ((const float4*)(y + (size_t)b * DD))[t];
    float s  = x.x + x.y + x.z + x.w;
    float s2 = x.x * x.x + x.y * x.y + x.z * x.z + x.w * x.w;
    __shared__ float rs[4], rs2[4];
    s = wave_sum(s); s2 = wave_sum(s2);
    const int w = t >> 6, lane = t & 63;
    if (lane == 0) { rs[w] = s; rs2[w] = s2; }
    __syncthreads();
    s  = rs[0] + rs[1] + rs[2] + rs[3];
    s2 = rs2[0] + rs2[1] + rs2[2] + rs2[3];
    const float mu  = s * (1.0f / DD);
    const float var = s2 * (1.0f / DD) - mu * mu;
    const float rstd = rsqrtf(var + 1e-5f);
    const float4 w4 = ((const float4*)on_w)[t];
    const float4 b4 = ((const float4*)on_b)[t];
    float4 o;
    o.x = (x.x - mu) * rstd * w4.x + b4.x;
    o.y = (x.y - mu) * rstd * w4.y + b4.y;
    o.z = (x.z - mu) * rstd * w4.z + b4.z;
    o.w = (x.w - mu) * rstd * w4.w + b4.w;
    ((float4*)(outp + (size_t)b * DD))[t] = o;
}

extern "C" void kernel_launch(void* const* d_in, const int* in_sizes, int n_in,
                              void* d_out, int out_size, void* d_ws, size_t ws_size,
                              hipStream_t stream) {
    const float* gr   = (const float*)d_in[0];
    const float* sq   = (const float*)d_in[1];
    const float* qn_w = (const float*)d_in[2];
    const float* qn_b = (const float*)d_in[3];
    const float* ipw  = (const float*)d_in[4];
    const float* ipb  = (const float*)d_in[5];
    const float* ow   = (const float*)d_in[6];
    const float* ob   = (const float*)d_in[7];
    const float* on_w = (const float*)d_in[8];
    const float* on_b = (const float*)d_in[9];
    const int*   pos  = (const int*)d_in[10];

    float* out  = (float*)d_out;
    float* attn = out + BB * DD;           // output 1 region; holds exp(score) until norm
    float* ws   = (float*)d_ws;

    k_q0<<<1, 256, 0, stream>>>(sq, qn_w, qn_b, pos, ws);
    k_q<<<256, 256, 0, stream>>>(ipw, ipb, ws);
    k_r<<<64, 256, 0, stream>>>(ipw, ipb, ws);
    k_fused<<<BB * NCK, 256, 0, stream>>>(gr, ws, attn, ws + WS_PART, ws + WS_SSUM);
    k_ctx<<<BB * HH, 256, 0, stream>>>(ipw, ipb, ws + WS_PART, ws + WS_SSUM,
                                       ws + WS_SINV, ws + WS_CTX);
    k_attn_norm<<<BB * HH, 256, 0, stream>>>(attn, ws + WS_SINV);
    k_y<<<BB * 16, 256, 0, stream>>>(ow, ob, ws + WS_CTX, ws + WS_Y);
    k_lnout<<<BB, 256, 0, stream>>>(ws + WS_Y, on_w, on_b, out);
}

// Round 4
// 181.512 us; speedup vs baseline: 3.1539x; 3.1539x over previous
//
#include <hip/hip_runtime.h>
#include <math.h>

#define BB 32
#define LL 2048
#define DD 1024
#define HH 16
#define DHH 64
#define NCK 32         // chunks per batch
#define CH  64         // rows per chunk

// ---- ws layout (float offsets) ----
#define WS_Q0    0          // 1024
#define WS_Q     1024       // 1024
#define WS_R     2048       // 16*1024
#define WS_C     18432      // 64 (16 used)
#define WS_SINV  18496      // 512
#define WS_CTX   19008      // 32768
#define WS_Y     51776      // 32768
#define WS_SSUM  84544      // 32*32*16 = 16384
#define WS_PART  100928     // 32*32*16*1024 = 16777216
// total ~= 16.9M floats ~= 67.5 MB (ws is ~1 GB)

__device__ __forceinline__ float wave_sum(float v) {
#pragma unroll
    for (int s = 32; s >= 1; s >>= 1) v += __shfl_xor(v, s, 64);
    return v;
}

// ---------------- K0: q0 = LN(symbol_queries[pos]) ----------------
__global__ void k_q0(const float* __restrict__ sq, const float* __restrict__ qn_w,
                     const float* __restrict__ qn_b, const int* __restrict__ pos,
                     float* __restrict__ ws) {
    const int t = threadIdx.x;              // 256 threads
    const float4 x = ((const float4*)(sq + (size_t)pos[0] * DD))[t];
    float s  = x.x + x.y + x.z + x.w;
    float s2 = x.x * x.x + x.y * x.y + x.z * x.z + x.w * x.w;
    __shared__ float rs[4], rs2[4];
    s = wave_sum(s); s2 = wave_sum(s2);
    const int w = t >> 6, lane = t & 63;
    if (lane == 0) { rs[w] = s; rs2[w] = s2; }
    __syncthreads();
    s  = rs[0] + rs[1] + rs[2] + rs[3];
    s2 = rs2[0] + rs2[1] + rs2[2] + rs2[3];
    const float mu  = s * (1.0f / DD);
    const float var = s2 * (1.0f / DD) - mu * mu;
    const float rstd = rsqrtf(var + 1e-5f);
    const float4 w4 = ((const float4*)qn_w)[t];
    const float4 b4 = ((const float4*)qn_b)[t];
    float4 o;
    o.x = (x.x - mu) * rstd * w4.x + b4.x;
    o.y = (x.y - mu) * rstd * w4.y + b4.y;
    o.z = (x.z - mu) * rstd * w4.z + b4.z;
    o.w = (x.w - mu) * rstd * w4.w + b4.w;
    ((float4*)(ws + WS_Q0))[t] = o;
}

// ---------------- K1: q = Wq @ q0 + bq  (wave per output) ----------------
__global__ void k_q(const float* __restrict__ ipw, const float* __restrict__ ipb,
                    float* __restrict__ ws) {
    const int w = threadIdx.x >> 6, lane = threadIdx.x & 63;
    const int d = blockIdx.x * 4 + w;       // 256 blocks * 4 waves = 1024 outputs
    const float* row = ipw + (size_t)d * DD;
    const float* q0 = ws + WS_Q0;
    float acc = 0.f;
#pragma unroll
    for (int it = 0; it < 4; ++it) {
        float4 a = ((const float4*)row)[lane + 64 * it];
        float4 b = ((const float4*)q0)[lane + 64 * it];
        acc += a.x * b.x + a.y * b.y + a.z * b.z + a.w * b.w;
    }
    acc = wave_sum(acc);
    if (lane == 0) (ws + WS_Q)[d] = acc + ipb[d];
}

// ---------------- K2: r_s[h,e] = scale * sum_j q[h,j] Wk[h*64+j, e] --------
// grid 64 = (h, quarter); 256 threads each own one e.
__global__ void k_r(const float* __restrict__ ipw, const float* __restrict__ ipb,
                    float* __restrict__ ws) {
    const int h = blockIdx.x >> 2, qa = blockIdx.x & 3;
    const int t = threadIdx.x;
    const int e = qa * 256 + t;
    const float* q = ws + WS_Q;
    const float* wk = ipw + (size_t)(DD + h * DHH) * DD;
    float acc = 0.f;
#pragma unroll 8
    for (int j = 0; j < DHH; ++j)
        acc += q[h * DHH + j] * wk[(size_t)j * DD + e];
    (ws + WS_R)[h * DD + e] = acc * 0.125f;
    if (qa == 0 && t < 64) {
        float p = q[h * DHH + t] * ipb[DD + h * DHH + t];
        p = wave_sum(p);
        if (t == 0) (ws + WS_C)[h] = p * 0.125f;
    }
}

// ---------------- fused: scores + exp + weighted pooling, one grid pass ----
// block = (b, chunk of 64 rows); 256 threads; thread owns float4 e-slice.
// NOTE: __launch_bounds__(256, 2) is load-bearing: it yields the 124-VGPR
// no-spill codegen (R2). (256, 4) clamps to 64 VGPR and spills ~2 GB (R3).
__global__ __launch_bounds__(256, 2)
void k_fused(const float* __restrict__ gr, const float* __restrict__ ws,
             float* __restrict__ attn_e, float* __restrict__ part,
             float* __restrict__ ssum) {
    const int b  = blockIdx.x >> 5;
    const int ck = blockIdx.x & 31;
    const int l0 = ck * CH;
    const int t = threadIdx.x, w = t >> 6, lane = t & 63;
    float4 rr[16];
#pragma unroll
    for (int h = 0; h < 16; ++h) rr[h] = ((const float4*)(ws + WS_R + h * DD))[t];
    const float myc = (ws + WS_C)[lane >> 2];
    float4 acc[16];
#pragma unroll
    for (int h = 0; h < 16; ++h) acc[h] = make_float4(0.f, 0.f, 0.f, 0.f);
    float s_loc = 0.f;                      // (w0 lanes) sum of weights for (h,j)
    float* outp = attn_e + (size_t)b * (HH * LL) + (size_t)(lane >> 2) * LL + l0 + (lane & 3);
    const float* gb = gr + ((size_t)b * LL + l0) * DD;
    __shared__ float red[4][64];
    __shared__ float wbuf[64];

    float4 gv[4];
#pragma unroll
    for (int j = 0; j < 4; ++j)
        gv[j] = ((const float4*)(gb + (size_t)j * DD))[t];

    for (int g = 0; g < CH / 4; ++g) {
        // ---- scores for 4 rows x 16 heads ----
        float val[64];                      // v = h*4 + j
#pragma unroll
        for (int h = 0; h < 16; ++h)
#pragma unroll
            for (int j = 0; j < 4; ++j)
                val[h * 4 + j] = rr[h].x * gv[j].x + rr[h].y * gv[j].y +
                                 rr[h].z * gv[j].z + rr[h].w * gv[j].w;
        // multi-value butterfly: lane i ends holding total of value i
#pragma unroll
        for (int step = 0; step < 6; ++step) {
            const int s = 32 >> step;
            const bool up = (lane & s) != 0;
#pragma unroll
            for (int k = 0; k < (32 >> step); ++k) {
                float send = up ? val[k] : val[k + s];
                float recv = __shfl_xor(send, s, 64);
                float mine = up ? val[k + s] : val[k];
                val[k] = mine + recv;
            }
        }
        red[w][lane] = val[0];
        __syncthreads();
        if (w == 0) {
            float tot = red[0][lane] + red[1][lane] + red[2][lane] + red[3][lane] + myc;
            float wv = __expf(tot);         // no max-shift: |score| ~ O(1)
            outp[g * 4] = wv;
            s_loc += wv;
            wbuf[lane] = wv;
        }
        __syncthreads();
        // ---- prefetch next group's rows ----
        float4 gn[4];
        if (g < CH / 4 - 1) {
#pragma unroll
            for (int j = 0; j < 4; ++j)
                gn[j] = ((const float4*)(gb + (size_t)((g + 1) * 4 + j) * DD))[t];
        }
        // ---- weighted accumulation (weights broadcast from LDS) ----
#pragma unroll
        for (int h = 0; h < 16; ++h) {
            const float4 w4 = ((const float4*)wbuf)[h];
            acc[h].x += w4.x * gv[0].x + w4.y * gv[1].x + w4.z * gv[2].x + w4.w * gv[3].x;
            acc[h].y += w4.x * gv[0].y + w4.y * gv[1].y + w4.z * gv[2].y + w4.w * gv[3].y;
            acc[h].z += w4.x * gv[0].z + w4.y * gv[1].z + w4.z * gv[2].z + w4.w * gv[3].z;
            acc[h].w += w4.x * gv[0].w + w4.y * gv[1].w + w4.z * gv[2].w + w4.w * gv[3].w;
        }
#pragma unroll
        for (int j = 0; j < 4; ++j) gv[j] = gn[j];
    }
    // ---- write weight sums (w0) and partials ----
    if (w == 0) {
        float v = s_loc;
        v += __shfl_xor(v, 1, 64);
        v += __shfl_xor(v, 2, 64);
        if ((lane & 3) == 0) ssum[((size_t)b * NCK + ck) * HH + (lane >> 2)] = v;
    }
    float* pp = part + ((size_t)b * NCK + ck) * (HH * DD);
#pragma unroll
    for (int h = 0; h < 16; ++h) ((float4*)(pp + h * DD))[t] = acc[h];
}

// ---------------- combine + Wv: ctx[b, h*64+j] ----------------
__global__ void k_ctx(const float* __restrict__ ipw, const float* __restrict__ ipb,
                      const float* __restrict__ part, const float* __restrict__ ssum,
                      float* __restrict__ sinv_out, float* __restrict__ ctx) {
    const int bh = blockIdx.x, b = bh >> 4, h = bh & 15;   // 512 blocks
    const int t = threadIdx.x, w = t >> 6, lane = t & 63;  // 256
    float S = 0.f;
#pragma unroll
    for (int c = 0; c < NCK; ++c) S += ssum[((size_t)b * NCK + c) * HH + h];
    const float inv = 1.0f / S;
    if (t == 0) sinv_out[bh] = inv;
    __shared__ float Xl[DD];
    float4 x = {0.f, 0.f, 0.f, 0.f};
#pragma unroll
    for (int c = 0; c < NCK; ++c) {
        float4 p = ((const float4*)(part + ((size_t)b * NCK + c) * (HH * DD) + h * DD))[t];
        x.x += p.x; x.y += p.y; x.z += p.z; x.w += p.w;
    }
    float4 xs = {x.x * inv, x.y * inv, x.z * inv, x.w * inv};
    ((float4*)Xl)[t] = xs;
    __syncthreads();
    for (int jj = 0; jj < 16; ++jj) {
        const int j = w * 16 + jj;
        const float* row = ipw + (size_t)(2 * DD + h * DHH + j) * DD;
        float acc = 0.f;
#pragma unroll
        for (int it = 0; it < 4; ++it) {
            float4 a = ((const float4*)row)[lane + 64 * it];
            float4 p = ((const float4*)Xl)[lane + 64 * it];
            acc += a.x * p.x + a.y * p.y + a.z * p.z + a.w * p.w;
        }
        acc = wave_sum(acc);
        if (lane == 0) ctx[(size_t)b * DD + h * DHH + j] = acc + ipb[2 * DD + h * DHH + j];
    }
}

// ---------------- normalize attn in place: *= 1/S ----------------
__global__ void k_attn_norm(float* __restrict__ attn_e, const float* __restrict__ sinv) {
    const int bh = blockIdx.x;              // 512
    const int t = threadIdx.x;              // 256
    const float inv = sinv[bh];
    float4* p = (float4*)(attn_e + (size_t)bh * LL);
#pragma unroll
    for (int i = 0; i < 2; ++i) {
        float4 v = p[t + 256 * i];
        v.x *= inv; v.y *= inv; v.z *= inv; v.w *= inv;
        p[t + 256 * i] = v;
    }
}

// ---------------- y[b, d'] = out_w[d',:]·ctx[b,:] + out_b ----------------
__global__ void k_y(const float* __restrict__ ow, const float* __restrict__ ob,
                    const float* __restrict__ ctx, float* __restrict__ y) {
    const int blk = blockIdx.x, b = blk >> 4, ch = blk & 15;  // 512 blocks
    const int t = threadIdx.x, w = t >> 6, lane = t & 63;     // 256
    __shared__ float Xl[DD];
    ((float4*)Xl)[t] = ((const float4*)(ctx + (size_t)b * DD))[t];
    __syncthreads();
    for (int jj = 0; jj < 16; ++jj) {
        const int d = ch * 64 + w * 16 + jj;
        const float* row = ow + (size_t)d * DD;
        float acc = 0.f;
#pragma unroll
        for (int it = 0; it < 4; ++it) {
            float4 a = ((const float4*)row)[lane + 64 * it];
            float4 p = ((const float4*)Xl)[lane + 64 * it];
            acc += a.x * p.x + a.y * p.y + a.z * p.z + a.w * p.w;
        }
        acc = wave_sum(acc);
        if (lane == 0) y[(size_t)b * DD + d] = acc + ob[d];
    }
}

// ---------------- final LN -> pooled output ----------------
__global__ void k_lnout(const float* __restrict__ y, const float* __restrict__ on_w,
                        const float* __restrict__ on_b, float* __restrict__ outp) {
    const int b = blockIdx.x, t = threadIdx.x;   // 32 blocks, 256 threads
    const float4 x = ((const float4*)(y + (size_t)b * DD))[t];
    float s  = x.x + x.y + x.z + x.w;
    float s2 = x.x * x.x + x.y * x.y + x.z * x.z + x.w * x.w;
    __shared__ float rs[4], rs2[4];
    s = wave_sum(s); s2 = wave_sum(s2);
    const int w = t >> 6, lane = t & 63;
    if (lane == 0) { rs[w] = s; rs2[w] = s2; }
    __syncthreads();
    s  = rs[0] + rs[1] + rs[2] + rs[3];
    s2 = rs2[0] + rs2[1] + rs2[2] + rs2[3];
    const float mu  = s * (1.0f / DD);
    const float var = s2 * (1.0f / DD) - mu * mu;
    const float rstd = rsqrtf(var + 1e-5f);
    const float4 w4 = ((const float4*)on_w)[t];
    const float4 b4 = ((const float4*)on_b)[t];
    float4 o;
    o.x = (x.x - mu) * rstd * w4.x + b4.x;
    o.y = (x.y - mu) * rstd * w4.y + b4.y;
    o.z = (x.z - mu) * rstd * w4.z + b4.z;
    o.w = (x.w - mu) * rstd * w4.w + b4.w;
    ((float4*)(outp + (size_t)b * DD))[t] = o;
}

extern "C" void kernel_launch(void* const* d_in, const int* in_sizes, int n_in,
                              void* d_out, int out_size, void* d_ws, size_t ws_size,
                              hipStream_t stream) {
    const float* gr   = (const float*)d_in[0];
    const float* sq   = (const float*)d_in[1];
    const float* qn_w = (const float*)d_in[2];
    const float* qn_b = (const float*)d_in[3];
    const float* ipw  = (const float*)d_in[4];
    const float* ipb  = (const float*)d_in[5];
    const float* ow   = (const float*)d_in[6];
    const float* ob   = (const float*)d_in[7];
    const float* on_w = (const float*)d_in[8];
    const float* on_b = (const float*)d_in[9];
    const int*   pos  = (const int*)d_in[10];

    float* out  = (float*)d_out;
    float* attn = out + BB * DD;           // output 1 region; holds exp(score) until norm
    float* ws   = (float*)d_ws;

    k_q0<<<1, 256, 0, stream>>>(sq, qn_w, qn_b, pos, ws);
    k_q<<<256, 256, 0, stream>>>(ipw, ipb, ws);
    k_r<<<64, 256, 0, stream>>>(ipw, ipb, ws);
    k_fused<<<BB * NCK, 256, 0, stream>>>(gr, ws, attn, ws + WS_PART, ws + WS_SSUM);
    k_ctx<<<BB * HH, 256, 0, stream>>>(ipw, ipb, ws + WS_PART, ws + WS_SSUM,
                                       ws + WS_SINV, ws + WS_CTX);
    k_attn_norm<<<BB * HH, 256, 0, stream>>>(attn, ws + WS_SINV);
    k_y<<<BB * 16, 256, 0, stream>>>(ow, ob, ws + WS_CTX, ws + WS_Y);
    k_lnout<<<BB, 256, 0, stream>>>(ws + WS_Y, on_w, on_b, out);
}